// Round 10
// baseline (156.182 us; speedup 1.0000x reference)
//
#include <hip/hip_runtime.h>

// Median filter (k=22, REFLECT) + blend, NHWC (2,224,224,3) fp32.
// One wave per 8 consecutive-x pixels, processed as 4 PAIRS in lockstep.
// Window (484) in 8 regs/lane; ballot counting.
// V10 = V9 (113.8us, ties V4 as best) with the cross-lane reduce rebuilt:
//  - DPP WAVE MAX: the peel's 7-serial-DS reduce (bpermute-xor32 + 5-stage
//    ds_swizzle butterfly, ~200cy/round) is replaced by AMD's canonical
//    6-op DPP max chain (row_shr:1/2/4/8 + row_bcast:15 + row_bcast:31,
//    result in lane 63) — pure VALU, ~4cy/step, zero DS. A/B chains are
//    independent and interleave. bound_ctrl=false + old=src => lanes with
//    no DPP source keep their own value (max-preserving); lane63 coverage
//    is exact. V4..V9 showed op-count cuts no longer move time (114us
//    plateau, VALUBusy 70->78%): the DS chain latency is the fence.
//  - BRACKETED NEWTON probes (V9-proven): lo/hi bracket + midpoint fallback
//    is the convergence guarantee; step tn = fma(d,-1/AREA,t) clamped.
//  - e==1 FAST PATH + BYTE-OFFSET gather (proven absmax 0).
// DT=2, pair lockstep, one group/wave (9408 blocks) — all proven.

#define HH 224
#define WW 224
#define CHN 3
#define KK 22
#define PT 10            // pad top/left; bottom/right = 11
#define AREA (KK * KK)   // 484
#define RANK 242         // median = 242nd smallest (1-indexed)
#define PXW 8
#define XGS (WW / PXW)   // 28
#define DT 2             // stop probing when |count-RANK| <= DT
#define NGROUPS (2 * CHN * HH * XGS)   // 37632
#define XSB (CHN * 4)    // bytes per x-step (12)

#define INFF  __int_as_float(0x7f800000)
#define NINFF __int_as_float(0xff800000)

__device__ __forceinline__ int reflect224(int g) {
    int a = abs(g);
    return min(a, 2 * (HH - 1) - a);
}

__device__ __forceinline__ int count8(const float v[8], float t) {
    int c = 0;
#pragma unroll
    for (int i = 0; i < 8; ++i)
        c += __popcll(__ballot(v[i] < t));
    return c;
}

// in-lane tree max over the 8 window regs
__device__ __forceinline__ float tree8(const float v[8]) {
    return fmaxf(fmaxf(fmaxf(v[0], v[1]), fmaxf(v[2], v[3])),
                 fmaxf(fmaxf(v[4], v[5]), fmaxf(v[6], v[7])));
}

// one DPP max-accumulate step; ctrl must be a literal. old=src +
// bound_ctrl=false => lanes w/o a valid source keep their own value.
#define DPPMAX(x, ctrl)                                                      \
    x = fmaxf(x, __int_as_float(__builtin_amdgcn_update_dpp(                 \
            __float_as_int(x), __float_as_int(x), ctrl, 0xF, 0xF, false)));

// full 64-lane max, result valid in lane 63 (AMD canonical DPP reduce).
__device__ __forceinline__ float wave_max64(float x) {
    DPPMAX(x, 0x111)   // row_shr:1
    DPPMAX(x, 0x112)   // row_shr:2
    DPPMAX(x, 0x114)   // row_shr:4
    DPPMAX(x, 0x118)   // row_shr:8   -> lane15 of each row = row max
    DPPMAX(x, 0x142)   // row_bcast:15 -> lane31 = max(0..31), lane47,63 fold
    DPPMAX(x, 0x143)   // row_bcast:31 -> lane63 = max of all 64
    return x;
}

__device__ __forceinline__ float rdlane(float x, int l) {
    return __int_as_float(__builtin_amdgcn_readlane(__float_as_int(x), l));
}

// voffB holds BYTE offsets: gy*WW*CHN*4 + col*CHN*4 (vertical reflect baked)
__device__ __forceinline__ void gather(float v[8], const char* __restrict__ imgb,
                                       const int voffB[8], int lane, int x) {
    if (x >= PT && x <= WW - 1 - (KK - 1 - PT)) {      // interior: x in [10,212]
        const char* base = imgb + (x - PT) * XSB;      // wave-uniform base
#pragma unroll
        for (int i = 0; i < 8; ++i)
            v[i] = *(const float*)(base + voffB[i]);
    } else {
#pragma unroll
        for (int i = 0; i < 8; ++i) {
            int s   = i * 64 + lane;
            int se  = min(s, AREA - 1);
            int row = se / KK;
            int col = se - row * KK;
            int rowB = voffB[i] - col * XSB;
            int gx  = reflect224(x - PT + col);
            v[i] = *(const float*)(imgb + rowB + gx * XSB);
        }
    }
    v[7] = (lane < AREA - 448) ? v[7] : INFF;          // slots >= 484 -> +INF
}

// one bracketed-Newton probe step (V4's bracket, constant-slope step)
#define PROBE(vX, tX, dX, loX, hiX, actX)               \
    if (actX) {                                         \
        if (dX > 0) hiX = tX; else loX = tX;            \
        float tn_ = fmaf((float)dX, NINV, tX);          \
        if (!(tn_ > loX && tn_ < hiX)) tn_ = 0.5f * (loX + hiX); \
        if (!(tn_ > loX && tn_ < hiX)) actX = false;    \
        else {                                          \
            tX = tn_;                                   \
            dX = count8(vX, tX) - RANK;                 \
            actX = (dX > DT || dX < -DT);               \
        }                                               \
    }

// sign-fold in place: top (d>=0) keeps {v<t}; bottom keeps -{v>=t}
#define FOLD(vX, tX, topX)                                                   \
    if (topX) {                                                              \
        _Pragma("unroll")                                                    \
        for (int i_ = 0; i_ < 8; ++i_)                                       \
            vX[i_] = (vX[i_] < tX) ? vX[i_] : ninf;                          \
    } else {                                                                 \
        _Pragma("unroll")                                                    \
        for (int i_ = 0; i_ < 8; ++i_)                                       \
            vX[i_] = (vX[i_] < tX) ? ninf : -vX[i_];                         \
    }

// one peel resolution step for one pixel given its wave max mX
#define PEELSTEP(vX, eX, sgnX, medX, doneX, mX)                              \
    if (!doneX) {                                                            \
        if (eX == 1) {                                                       \
            medX = __int_as_float(__float_as_int(mX) ^ sgnX);                \
            doneX = true;                                                    \
        } else {                                                             \
            int q_ = 0;                                                      \
            _Pragma("unroll")                                                \
            for (int i_ = 0; i_ < 8; ++i_)                                   \
                q_ += __popcll(__ballot(vX[i_] == mX));                      \
            if (eX <= q_) {                                                  \
                medX = __int_as_float(__float_as_int(mX) ^ sgnX);            \
                doneX = true;                                                \
            } else {                                                         \
                eX -= q_;                                                    \
                _Pragma("unroll")                                            \
                for (int i_ = 0; i_ < 8; ++i_)                               \
                    vX[i_] = (vX[i_] == mX) ? ninf : vX[i_];                 \
            }                                                                \
        }                                                                    \
    }

__global__ __launch_bounds__(256)
void median_blend_kernel(const float* __restrict__ in,
                         const float* __restrict__ blend,
                         float* __restrict__ out) {
    const int lane = threadIdx.x & 63;
    const int wid  = threadIdx.x >> 6;
    const int wg = blockIdx.x * 4 + wid;        // wave-uniform group id
    // wg = ((b*CHN + c)*HH + y)*XGS + xg
    const int xg = wg % XGS;
    const int t1 = wg / XGS;
    const int y  = t1 % HH;
    const int t2 = t1 / HH;
    const int c  = t2 % CHN;
    const int b  = t2 / CHN;

    const float f = blend[0];
    const float* img  = in  + (size_t)b * (HH * WW * CHN) + c;
    float*       outp = out + (size_t)b * (HH * WW * CHN) + c;
    const char*  imgb = (const char*)img;

    // per-wave lane constants: BYTE voff = gy*2688 + col*12
    int voffB[8];
#pragma unroll
    for (int i = 0; i < 8; ++i) {
        int s   = i * 64 + lane;
        int se  = min(s, AREA - 1);
        int row = se / KK;
        int col = se - row * KK;
        int gy  = reflect224(y - PT + row);
        voffB[i] = gy * (WW * XSB) + col * XSB;
    }

    const float ninf = NINFF;
    const float NINV = -1.0f / (float)AREA;     // Newton slope: -1/484

    const int x0 = xg * PXW;
    float tprev = 0.5f;

#pragma unroll 1
    for (int j = 0; j < PXW; j += 2) {
        const int xA = x0 + j;
        const int xB = xA + 1;

        float vA[8], vB[8];
        gather(vA, imgb, voffB, lane, xA);
        gather(vB, imgb, voffB, lane, xB);

        // ---- warm-started bracketed-Newton probes, pair lockstep ----
        float tA = tprev, tB = tprev;
        int dA = count8(vA, tA) - RANK;
        int dB = count8(vB, tB) - RANK;
        float loA = 0.0f, hiA = 1.0f, loB = 0.0f, hiB = 1.0f;
        bool actA = (dA > DT || dA < -DT), actB = (dB > DT || dB < -DT);
#pragma unroll 1
        for (int it = 0; it < 16 && (actA || actB); ++it) {
            PROBE(vA, tA, dA, loA, hiA, actA)
            PROBE(vB, tB, dB, loB, hiB, actB)
        }

        // ---- pair sign-folded max-peel, DPP reduce ----
        // top (d>=0): (d+1)-th largest of {v<t}; bottom: (-d)-th smallest of
        // {v>=t} == peel max of -v. Exact for any (t,d).
        const bool topA = (dA >= 0), topB = (dB >= 0);
        int eA = topA ? dA + 1 : -dA;
        int eB = topB ? dB + 1 : -dB;
        const int sgnA = topA ? 0 : (int)0x80000000;
        const int sgnB = topB ? 0 : (int)0x80000000;
        FOLD(vA, tA, topA)
        FOLD(vB, tB, topB)
        // (+INF sentinels: top -> excluded; bottom -> fold to -INF, never
        //  selected since e <= #real candidates.)

        float medA = tA, medB = tB;               // provably overwritten
        bool doneA = false, doneB = false;
#pragma unroll 1
        for (int r = 0; r < 300 && !(doneA && doneB); ++r) {
            float pA = doneA ? ninf : tree8(vA);
            float pB = doneB ? ninf : tree8(vB);
            pA = wave_max64(pA);                  // two independent DPP chains
            pB = wave_max64(pB);                  //   -> latencies interleave
            const float mA = rdlane(pA, 63);
            const float mB = rdlane(pB, 63);
            PEELSTEP(vA, eA, sgnA, medA, doneA, mA)
            PEELSTEP(vB, eB, sgnB, medB, doneB, mB)
        }
        tprev = medB;                              // warm start for next pair

        // ---- blend + store ----
        const float xcA = img[y * (WW * CHN) + xA * CHN];
        const float xcB = img[y * (WW * CHN) + xB * CHN];
        if (lane == 0) {
            outp[y * (WW * CHN) + xA * CHN] = medA + f * (xcA - medA);
            outp[y * (WW * CHN) + xB * CHN] = medB + f * (xcB - medB);
        }
    }
}

extern "C" void kernel_launch(void* const* d_in, const int* in_sizes, int n_in,
                              void* d_out, int out_size, void* d_ws, size_t ws_size,
                              hipStream_t stream) {
    const float* in    = (const float*)d_in[0];
    const float* blend = (const float*)d_in[1];
    float* out = (float*)d_out;

    const int nblocks = NGROUPS / 4;           // 9408, one group per wave
    median_blend_kernel<<<nblocks, 256, 0, stream>>>(in, blend, out);
}